// Round 5
// baseline (174.435 us; speedup 1.0000x reference)
//
#include <hip/hip_runtime.h>
#include <stdint.h>

#define NB 4
#define NN 512
#define NC 64
#define NH 128
#define NCO 64
#define MAXM 64          // fast-path cap on valid count
#define STR4 17          // float4 stride per channel row (odd -> perfect bank spread)

// mask dtype decode: int32 (w0==1), float32 (w0==0x3f800000), else packed bytes.
__device__ inline bool read_mask(const void* mp, int idx) {
    const int* ip = (const int*)mp;
    int w0 = ip[0];
    if (w0 == 1) return ip[idx] != 0;
    if (w0 == 0x3f800000) return ((const float*)mp)[idx] != 0.0f;
    return ((const unsigned char*)mp)[idx] != 0;
}

// One wave per row: neighbor census -> validbits = neighbors surviving row i's
// own dilation removal (self excluded). valid(i,j) = vb_i[j] && vb_j[i].
// Blocks 0..63 also transpose W1/W2.
__global__ __launch_bounds__(256) void prep_kernel(
        const float* __restrict__ adj, const void* __restrict__ maskp,
        const float* __restrict__ W1, const float* __restrict__ W2,
        uint64_t* __restrict__ validbits, float* __restrict__ W1T,
        float* __restrict__ W2T, int dowt)
{
    int wave = (blockIdx.x * 256 + threadIdx.x) >> 6;
    int lane = threadIdx.x & 63;
    if (wave < NB * NN) {
        int i = wave & (NN - 1);
        const float* arow = adj + (size_t)wave * NN;
        uint64_t ball[8];
        int m = 0;
        #pragma unroll
        for (int k = 0; k < 8; ++k) {
            int j = k * 64 + lane;
            bool f = (j != i) && (arow[j] > 0.0f);
            uint64_t bl = __ballot(f);
            ball[k] = bl;
            m += __popcll(bl);
        }
        int skip = (m > 10) ? ((m + 1) >> 1) : 1;   // ceil(m/2), K_DIL=2
        bool dodil = (skip > 1) && read_mask(maskp, wave);
        int skip2 = skip * 2;
        int prefix = 0;
        #pragma unroll
        for (int k = 0; k < 8; ++k) {
            uint64_t bl = ball[k];
            int rank1 = prefix + __popcll(bl & ((1ull << lane) - 1ull)) + 1;
            bool f = (bl >> lane) & 1ull;
            // (rank % skip)==0 <=> rank==skip || rank==2*skip  (rank <= m <= 2*skip)
            bool keep = f && !(dodil && (rank1 == skip || rank1 == skip2));
            uint64_t vb = __ballot(keep);
            if (lane == 0) validbits[(size_t)wave * 8 + k] = vb;
            prefix += __popcll(bl);
        }
    }
    if (dowt) {
        int e = blockIdx.x * 256 + threadIdx.x;
        if (e < 8192) {                       // W1T[k][c] = W1[c][k]
            int k = e >> 6, c = e & 63;
            W1T[e] = W1[c * NH + k];
        } else if (e < 16384) {               // W2T[o][k] = W2[k][o]
            int e2 = e - 8192;
            int o = e2 >> 7, k = e2 & 127;
            W2T[e2] = W2[k * NCO + o];
        }
    }
}

// One 256-thread block per row. Fixed-trip unrolled staging/ranking paths,
// conflict-free odd-stride staging, fused GIN MLP on overlaid LDS.
template<bool USE_WT>
__global__ __launch_bounds__(256, 8) void fused_kernel(
        const float* __restrict__ x,
        const void* __restrict__ maskp,
        const float* __restrict__ W1,
        const float* __restrict__ b1,
        const float* __restrict__ W2,
        const float* __restrict__ b2,
        const uint64_t* __restrict__ validbits,
        const float* __restrict__ W1T,
        const float* __restrict__ W2T,
        float* __restrict__ out)
{
    int row = blockIdx.x;                // b*NN + i
    int b = row >> 9, i = row & (NN - 1);
    int tid = threadIdx.x, lane = tid & 63, wv = tid >> 6;
    float* outp = out + (size_t)row * NCO;

    if (!read_mask(maskp, row)) {        // masked row: explicit zeros (out poisoned)
        if (tid < NCO) outp[tid] = 0.0f;
        return;
    }

    __shared__ float4 s_q4[NC * STR4];           // 17408 B; reused as MLP scratch
    __shared__ float s_qv[NC * 8];               // 2 KB quantile slots
    __shared__ __align__(8) uint16_t s_idx[MAXM];// valid list (unordered)
    __shared__ uint64_t s_vb[8];                 // row i's validbits (no self)
    __shared__ uint64_t s_vf[8];                 // full pairwise-valid bits (w/ self)
    __shared__ int s_cnt;

    float xval = (tid < NC) ? x[(size_t)row * NC + tid] : 0.0f;  // prefetch
    if (tid < 8) s_vb[tid] = validbits[(size_t)row * 8 + tid];
    if (tid < MAXM) s_idx[tid] = (uint16_t)i;    // safe-address padding; slot 0=self
    if (tid == 0) s_cnt = 1;
    __syncthreads();

    // ---- P2: valid(i,j) = vb_i[j] && vb_j[i]; list append + full-valid ballot ----
    int ic = i >> 6;
    uint64_t imask = 1ull << (i & 63);
    #pragma unroll
    for (int it = 0; it < 2; ++it) {
        int j = tid + it * 256;
        bool nb = ((s_vb[j >> 6] >> (j & 63)) & 1ull) &&
                  (validbits[((size_t)(b * NN + j)) * 8 + ic] & imask);
        uint64_t bl = __ballot(nb || (j == i));
        if (lane == 0) s_vf[it * 4 + wv] = bl;
        if (nb) {
            int p = atomicAdd(&s_cnt, 1);
            if (p < MAXM) s_idx[p] = (uint16_t)j;
        }
    }
    __syncthreads();
    int m = s_cnt;                       // >= 1 (self-loop)

    // ---- quantile positions (torch 'linear') ----
    float mf = (float)m;
    const float taus[3] = {0.25f, 0.5f, 0.75f};
    const float wts[3]  = {0.25f, 0.5f, 0.25f};
    int tlo[3], thi[3];
    float tfrac[3];
    #pragma unroll
    for (int t = 0; t < 3; ++t) {
        float pos = taus[t] * (mf - 1.0f);
        float fl = floorf(pos);
        tlo[t] = (int)fl;
        thi[t] = (int)ceilf(pos);
        tfrac[t] = pos - fl;
    }

    const float* xb = x + (size_t)b * NN * NC;

    // ---- P3+P4: fixed-trip unrolled stage & rank. Value occupies sorted
    // ranks [rs, rl). Pads (3e38) land at [m, ...) -> never selected. ----
    if (m <= 32) {
        #pragma unroll
        for (int h = 0; h < 2; ++h) {            // quads u = wv, wv+4
            int u = wv + 4 * h;
            ushort4 id4 = ((const ushort4*)s_idx)[u];
            float v0 = xb[(int)id4.x * NC + lane];
            float v1 = xb[(int)id4.y * NC + lane];
            float v2 = xb[(int)id4.z * NC + lane];
            float v3 = xb[(int)id4.w * NC + lane];
            int j0 = u * 4;
            float4 f;
            f.x = (j0 + 0 < m) ? v0 : 3.0e38f;
            f.y = (j0 + 1 < m) ? v1 : 3.0e38f;
            f.z = (j0 + 2 < m) ? v2 : 3.0e38f;
            f.w = (j0 + 3 < m) ? v3 : 3.0e38f;
            s_q4[lane * STR4 + u] = f;           // b128, bank-quad (lane+u)%8
        }
        __syncthreads();
        const float4* basep = s_q4 + lane * STR4;
        #pragma unroll
        for (int h = 0; h < 2; ++h) {
            int cq = wv + 4 * h;
            float4 c4 = basep[cq];
            int rs0=0,rl0=0, rs1=0,rl1=0, rs2=0,rl2=0, rs3=0,rl3=0;
            #pragma unroll
            for (int jq = 0; jq < 8; ++jq) {
                float4 v = basep[jq];
                rs0 += (v.x <  c4.x)+(v.y <  c4.x)+(v.z <  c4.x)+(v.w <  c4.x);
                rl0 += (v.x <= c4.x)+(v.y <= c4.x)+(v.z <= c4.x)+(v.w <= c4.x);
                rs1 += (v.x <  c4.y)+(v.y <  c4.y)+(v.z <  c4.y)+(v.w <  c4.y);
                rl1 += (v.x <= c4.y)+(v.y <= c4.y)+(v.z <= c4.y)+(v.w <= c4.y);
                rs2 += (v.x <  c4.z)+(v.y <  c4.z)+(v.z <  c4.z)+(v.w <  c4.z);
                rl2 += (v.x <= c4.z)+(v.y <= c4.z)+(v.z <= c4.z)+(v.w <= c4.z);
                rs3 += (v.x <  c4.w)+(v.y <  c4.w)+(v.z <  c4.w)+(v.w <  c4.w);
                rl3 += (v.x <= c4.w)+(v.y <= c4.w)+(v.z <= c4.w)+(v.w <= c4.w);
            }
            float ce[4] = {c4.x, c4.y, c4.z, c4.w};
            int rsa[4] = {rs0, rs1, rs2, rs3};
            int rla[4] = {rl0, rl1, rl2, rl3};
            #pragma unroll
            for (int q = 0; q < 4; ++q) {
                #pragma unroll
                for (int t = 0; t < 3; ++t) {
                    if (rsa[q] <= tlo[t] && tlo[t] < rla[q]) s_qv[lane*8 + 2*t]   = ce[q];
                    if (rsa[q] <= thi[t] && thi[t] < rla[q]) s_qv[lane*8 + 2*t+1] = ce[q];
                }
            }
        }
    } else if (m <= MAXM) {
        #pragma unroll
        for (int h = 0; h < 4; ++h) {            // quads u = wv, wv+4, wv+8, wv+12
            int u = wv + 4 * h;
            ushort4 id4 = ((const ushort4*)s_idx)[u];
            float v0 = xb[(int)id4.x * NC + lane];
            float v1 = xb[(int)id4.y * NC + lane];
            float v2 = xb[(int)id4.z * NC + lane];
            float v3 = xb[(int)id4.w * NC + lane];
            int j0 = u * 4;
            float4 f;
            f.x = (j0 + 0 < m) ? v0 : 3.0e38f;
            f.y = (j0 + 1 < m) ? v1 : 3.0e38f;
            f.z = (j0 + 2 < m) ? v2 : 3.0e38f;
            f.w = (j0 + 3 < m) ? v3 : 3.0e38f;
            s_q4[lane * STR4 + u] = f;
        }
        __syncthreads();
        const float4* basep = s_q4 + lane * STR4;
        #pragma unroll
        for (int h = 0; h < 4; ++h) {
            int cq = wv + 4 * h;
            float4 c4 = basep[cq];
            int rs0=0,rl0=0, rs1=0,rl1=0, rs2=0,rl2=0, rs3=0,rl3=0;
            #pragma unroll
            for (int jq = 0; jq < 16; ++jq) {
                float4 v = basep[jq];
                rs0 += (v.x <  c4.x)+(v.y <  c4.x)+(v.z <  c4.x)+(v.w <  c4.x);
                rl0 += (v.x <= c4.x)+(v.y <= c4.x)+(v.z <= c4.x)+(v.w <= c4.x);
                rs1 += (v.x <  c4.y)+(v.y <  c4.y)+(v.z <  c4.y)+(v.w <  c4.y);
                rl1 += (v.x <= c4.y)+(v.y <= c4.y)+(v.z <= c4.y)+(v.w <= c4.y);
                rs2 += (v.x <  c4.z)+(v.y <  c4.z)+(v.z <  c4.z)+(v.w <  c4.z);
                rl2 += (v.x <= c4.z)+(v.y <= c4.z)+(v.z <= c4.z)+(v.w <= c4.z);
                rs3 += (v.x <  c4.w)+(v.y <  c4.w)+(v.z <  c4.w)+(v.w <  c4.w);
                rl3 += (v.x <= c4.w)+(v.y <= c4.w)+(v.z <= c4.w)+(v.w <= c4.w);
            }
            float ce[4] = {c4.x, c4.y, c4.z, c4.w};
            int rsa[4] = {rs0, rs1, rs2, rs3};
            int rla[4] = {rl0, rl1, rl2, rl3};
            #pragma unroll
            for (int q = 0; q < 4; ++q) {
                #pragma unroll
                for (int t = 0; t < 3; ++t) {
                    if (rsa[q] <= tlo[t] && tlo[t] < rla[q]) s_qv[lane*8 + 2*t]   = ce[q];
                    if (rsa[q] <= thi[t] && thi[t] < rla[q]) s_qv[lane*8 + 2*t+1] = ce[q];
                }
            }
        }
    } else {
        // correctness-only fallback (m > 64; never triggers on bench data)
        if (tid < NC) {
            int c = tid;
            for (int j1 = 0; j1 < NN; ++j1) {
                if (!((s_vf[j1 >> 6] >> (j1 & 63)) & 1ull)) continue;
                float v1 = xb[j1 * NC + c];
                int rs = 0, rl = 0;
                for (int j2 = 0; j2 < NN; ++j2) {
                    if (!((s_vf[j2 >> 6] >> (j2 & 63)) & 1ull)) continue;
                    float v2 = xb[j2 * NC + c];
                    rs += v2 < v1;
                    rl += v2 <= v1;
                }
                #pragma unroll
                for (int t = 0; t < 3; ++t) {
                    if (rs <= tlo[t] && tlo[t] < rl) s_qv[c*8 + 2*t]   = v1;
                    if (rs <= thi[t] && thi[t] < rl) s_qv[c*8 + 2*t+1] = v1;
                }
            }
        }
    }
    __syncthreads();

    // ---- MLP scratch overlays the (now dead) staging buffer ----
    float* s_mlp  = (float*)s_q4;
    float* s_out  = s_mlp;               // [0,64)
    float* s_h    = s_mlp + 64;          // [64,192)
    float* s_hp   = s_mlp + 256;         // [256,512)
    float* s_part = s_mlp + 512;         // [512,768)

    if (tid < NC) {                      // out = x + sum wt * lerp(q_lo, q_hi)
        float agg = 0.0f;
        #pragma unroll
        for (int t = 0; t < 3; ++t) {
            float q = s_qv[tid * 8 + 2 * t] * (1.0f - tfrac[t])
                    + s_qv[tid * 8 + 2 * t + 1] * tfrac[t];
            agg += wts[t] * q;
        }
        s_out[tid] = xval + agg;
    }
    __syncthreads();

    // ---- MLP1: 256 threads = 128 k x 2 cc-halves ----
    {
        int k = tid & 127, g = tid >> 7;
        float acc = 0.0f;
        if (USE_WT) {
            const float4* w = (const float4*)(W1T + k * 64 + g * 32);
            #pragma unroll
            for (int q = 0; q < 8; ++q) {
                float4 wq = w[q];
                int cc = g * 32 + q * 4;
                acc += wq.x * s_out[cc] + wq.y * s_out[cc + 1]
                     + wq.z * s_out[cc + 2] + wq.w * s_out[cc + 3];
            }
        } else {
            for (int cc = g * 32; cc < g * 32 + 32; ++cc)
                acc += s_out[cc] * W1[cc * NH + k];
        }
        s_hp[g * NH + k] = acc;
    }
    __syncthreads();
    if (tid < NH) {
        float a = s_hp[tid] + s_hp[NH + tid] + b1[tid];
        s_h[tid] = a > 0.0f ? a : 0.0f;
    }
    __syncthreads();

    // ---- MLP2: 256 threads = 64 o x 4 k-quarters ----
    {
        int o = tid & 63, g = tid >> 6;
        float acc = 0.0f;
        if (USE_WT) {
            const float4* w = (const float4*)(W2T + o * 128 + g * 32);
            #pragma unroll
            for (int q = 0; q < 8; ++q) {
                float4 wq = w[q];
                int k = g * 32 + q * 4;
                acc += wq.x * s_h[k] + wq.y * s_h[k + 1]
                     + wq.z * s_h[k + 2] + wq.w * s_h[k + 3];
            }
        } else {
            for (int k = g * 32; k < g * 32 + 32; ++k)
                acc += s_h[k] * W2[k * NCO + o];
        }
        s_part[g * NCO + o] = acc;
    }
    __syncthreads();
    if (tid < NCO)
        outp[tid] = s_part[tid] + s_part[64 + tid] + s_part[128 + tid]
                  + s_part[192 + tid] + b2[tid];
}

extern "C" void kernel_launch(void* const* d_in, const int* in_sizes, int n_in,
                              void* d_out, int out_size, void* d_ws, size_t ws_size,
                              hipStream_t stream) {
    const float* x   = (const float*)d_in[0];
    const float* adj = (const float*)d_in[1];
    const void* mask = d_in[2];
    const float* W1  = (const float*)d_in[3];
    const float* b1  = (const float*)d_in[4];
    const float* W2  = (const float*)d_in[5];
    const float* b2  = (const float*)d_in[6];
    float* out = (float*)d_out;

    uint64_t* validbits = (uint64_t*)d_ws;               // 128 KB
    float* W1T = (float*)((char*)d_ws + 131072);         // 32 KB
    float* W2T = W1T + 8192;                             // 32 KB
    int dowt = (ws_size >= 196608) ? 1 : 0;

    prep_kernel<<<512, 256, 0, stream>>>(adj, mask, W1, W2, validbits, W1T, W2T, dowt);
    if (dowt)
        fused_kernel<true><<<NB * NN, 256, 0, stream>>>(
            x, mask, W1, b1, W2, b2, validbits, W1T, W2T, out);
    else
        fused_kernel<false><<<NB * NN, 256, 0, stream>>>(
            x, mask, W1, b1, W2, b2, validbits, W1T, W2T, out);
}

// Round 6
// 124.121 us; speedup vs baseline: 1.4054x; 1.4054x over previous
//
#include <hip/hip_runtime.h>
#include <stdint.h>

#define NB 4
#define NN 512
#define NC 64
#define NH 128
#define NCO 64
#define MAXM 64          // fast-path cap on valid count
#define STR4 17          // float4 stride per channel row (odd -> perfect bank spread)

// mask dtype decode: int32 (w0==1), float32 (w0==0x3f800000), else packed bytes.
__device__ inline bool read_mask(const void* mp, int idx) {
    const int* ip = (const int*)mp;
    int w0 = ip[0];
    if (w0 == 1) return ip[idx] != 0;
    if (w0 == 0x3f800000) return ((const float*)mp)[idx] != 0.0f;
    return ((const unsigned char*)mp)[idx] != 0;
}

// One wave per row: neighbor census -> validbits = neighbors surviving row i's
// own dilation removal (self excluded). valid(i,j) = vb_i[j] && vb_j[i].
// Blocks 0..63 also transpose W1/W2.
__global__ __launch_bounds__(256) void prep_kernel(
        const float* __restrict__ adj, const void* __restrict__ maskp,
        const float* __restrict__ W1, const float* __restrict__ W2,
        uint64_t* __restrict__ validbits, float* __restrict__ W1T,
        float* __restrict__ W2T, int dowt)
{
    int wave = (blockIdx.x * 256 + threadIdx.x) >> 6;
    int lane = threadIdx.x & 63;
    if (wave < NB * NN) {
        int i = wave & (NN - 1);
        const float* arow = adj + (size_t)wave * NN;
        uint64_t ball[8];
        int m = 0;
        #pragma unroll
        for (int k = 0; k < 8; ++k) {
            int j = k * 64 + lane;
            bool f = (j != i) && (arow[j] > 0.0f);
            uint64_t bl = __ballot(f);
            ball[k] = bl;
            m += __popcll(bl);
        }
        int skip = (m > 10) ? ((m + 1) >> 1) : 1;   // ceil(m/2), K_DIL=2
        bool dodil = (skip > 1) && read_mask(maskp, wave);
        int skip2 = skip * 2;
        int prefix = 0;
        #pragma unroll
        for (int k = 0; k < 8; ++k) {
            uint64_t bl = ball[k];
            int rank1 = prefix + __popcll(bl & ((1ull << lane) - 1ull)) + 1;
            bool f = (bl >> lane) & 1ull;
            // (rank % skip)==0 <=> rank==skip || rank==2*skip  (rank <= m <= 2*skip)
            bool keep = f && !(dodil && (rank1 == skip || rank1 == skip2));
            uint64_t vb = __ballot(keep);
            if (lane == 0) validbits[(size_t)wave * 8 + k] = vb;
            prefix += __popcll(bl);
        }
    }
    if (dowt) {
        int e = blockIdx.x * 256 + threadIdx.x;
        if (e < 8192) {                       // W1T[k][c] = W1[c][k]
            int k = e >> 6, c = e & 63;
            W1T[e] = W1[c * NH + k];
        } else if (e < 16384) {               // W2T[o][k] = W2[k][o]
            int e2 = e - 8192;
            int o = e2 >> 7, k = e2 & 127;
            W2T[e2] = W2[k * NCO + o];
        }
    }
}

// One 256-thread block per row. Fixed-trip unrolled staging/ranking paths,
// conflict-free odd-stride staging, fused GIN MLP on overlaid LDS.
// launch_bounds(256,4): 128-VGPR budget. (256,8) caused catastrophic scratch
// spills (67 MB/launch) in round 5 — occupancy is NOT the binding constraint.
template<bool USE_WT>
__global__ __launch_bounds__(256, 4) void fused_kernel(
        const float* __restrict__ x,
        const void* __restrict__ maskp,
        const float* __restrict__ W1,
        const float* __restrict__ b1,
        const float* __restrict__ W2,
        const float* __restrict__ b2,
        const uint64_t* __restrict__ validbits,
        const float* __restrict__ W1T,
        const float* __restrict__ W2T,
        float* __restrict__ out)
{
    int row = blockIdx.x;                // b*NN + i
    int b = row >> 9, i = row & (NN - 1);
    int tid = threadIdx.x, lane = tid & 63, wv = tid >> 6;
    float* outp = out + (size_t)row * NCO;

    if (!read_mask(maskp, row)) {        // masked row: explicit zeros (out poisoned)
        if (tid < NCO) outp[tid] = 0.0f;
        return;
    }

    __shared__ float4 s_q4[NC * STR4];           // 17408 B; reused as MLP scratch
    __shared__ float s_qv[NC * 8];               // 2 KB quantile slots
    __shared__ __align__(8) uint16_t s_idx[MAXM];// valid list (unordered)
    __shared__ uint64_t s_vb[8];                 // row i's validbits (no self)
    __shared__ uint64_t s_vf[8];                 // full pairwise-valid bits (w/ self)
    __shared__ int s_cnt;

    float xval = (tid < NC) ? x[(size_t)row * NC + tid] : 0.0f;  // prefetch
    if (tid < 8) s_vb[tid] = validbits[(size_t)row * 8 + tid];
    if (tid < MAXM) s_idx[tid] = (uint16_t)i;    // safe-address padding; slot 0=self
    if (tid == 0) s_cnt = 1;
    __syncthreads();

    // ---- P2: valid(i,j) = vb_i[j] && vb_j[i]; list append + full-valid ballot ----
    int ic = i >> 6;
    uint64_t imask = 1ull << (i & 63);
    #pragma unroll
    for (int it = 0; it < 2; ++it) {
        int j = tid + it * 256;
        bool nb = ((s_vb[j >> 6] >> (j & 63)) & 1ull) &&
                  (validbits[((size_t)(b * NN + j)) * 8 + ic] & imask);
        uint64_t bl = __ballot(nb || (j == i));
        if (lane == 0) s_vf[it * 4 + wv] = bl;
        if (nb) {
            int p = atomicAdd(&s_cnt, 1);
            if (p < MAXM) s_idx[p] = (uint16_t)j;
        }
    }
    __syncthreads();
    int m = s_cnt;                       // >= 1 (self-loop)

    // ---- quantile positions (torch 'linear') ----
    float mf = (float)m;
    const float taus[3] = {0.25f, 0.5f, 0.75f};
    const float wts[3]  = {0.25f, 0.5f, 0.25f};
    int tlo[3], thi[3];
    float tfrac[3];
    #pragma unroll
    for (int t = 0; t < 3; ++t) {
        float pos = taus[t] * (mf - 1.0f);
        float fl = floorf(pos);
        tlo[t] = (int)fl;
        thi[t] = (int)ceilf(pos);
        tfrac[t] = pos - fl;
    }

    const float* xb = x + (size_t)b * NN * NC;

    // ---- P3+P4: fixed-trip unrolled stage & rank. Value occupies sorted
    // ranks [rs, rl). Pads (3e38) land at [m, ...) -> never selected. ----
    if (m <= 32) {
        #pragma unroll
        for (int h = 0; h < 2; ++h) {            // quads u = wv, wv+4
            int u = wv + 4 * h;
            ushort4 id4 = ((const ushort4*)s_idx)[u];
            float v0 = xb[(int)id4.x * NC + lane];
            float v1 = xb[(int)id4.y * NC + lane];
            float v2 = xb[(int)id4.z * NC + lane];
            float v3 = xb[(int)id4.w * NC + lane];
            int j0 = u * 4;
            float4 f;
            f.x = (j0 + 0 < m) ? v0 : 3.0e38f;
            f.y = (j0 + 1 < m) ? v1 : 3.0e38f;
            f.z = (j0 + 2 < m) ? v2 : 3.0e38f;
            f.w = (j0 + 3 < m) ? v3 : 3.0e38f;
            s_q4[lane * STR4 + u] = f;           // b128, bank-quad (lane+u)%8
        }
        __syncthreads();
        const float4* basep = s_q4 + lane * STR4;
        #pragma unroll
        for (int h = 0; h < 2; ++h) {
            int cq = wv + 4 * h;
            float4 c4 = basep[cq];
            int rs0=0,rl0=0, rs1=0,rl1=0, rs2=0,rl2=0, rs3=0,rl3=0;
            #pragma unroll
            for (int jq = 0; jq < 8; ++jq) {
                float4 v = basep[jq];
                rs0 += (v.x <  c4.x)+(v.y <  c4.x)+(v.z <  c4.x)+(v.w <  c4.x);
                rl0 += (v.x <= c4.x)+(v.y <= c4.x)+(v.z <= c4.x)+(v.w <= c4.x);
                rs1 += (v.x <  c4.y)+(v.y <  c4.y)+(v.z <  c4.y)+(v.w <  c4.y);
                rl1 += (v.x <= c4.y)+(v.y <= c4.y)+(v.z <= c4.y)+(v.w <= c4.y);
                rs2 += (v.x <  c4.z)+(v.y <  c4.z)+(v.z <  c4.z)+(v.w <  c4.z);
                rl2 += (v.x <= c4.z)+(v.y <= c4.z)+(v.z <= c4.z)+(v.w <= c4.z);
                rs3 += (v.x <  c4.w)+(v.y <  c4.w)+(v.z <  c4.w)+(v.w <  c4.w);
                rl3 += (v.x <= c4.w)+(v.y <= c4.w)+(v.z <= c4.w)+(v.w <= c4.w);
            }
            float ce[4] = {c4.x, c4.y, c4.z, c4.w};
            int rsa[4] = {rs0, rs1, rs2, rs3};
            int rla[4] = {rl0, rl1, rl2, rl3};
            #pragma unroll
            for (int q = 0; q < 4; ++q) {
                #pragma unroll
                for (int t = 0; t < 3; ++t) {
                    if (rsa[q] <= tlo[t] && tlo[t] < rla[q]) s_qv[lane*8 + 2*t]   = ce[q];
                    if (rsa[q] <= thi[t] && thi[t] < rla[q]) s_qv[lane*8 + 2*t+1] = ce[q];
                }
            }
        }
    } else if (m <= MAXM) {
        #pragma unroll
        for (int h = 0; h < 4; ++h) {            // quads u = wv, wv+4, wv+8, wv+12
            int u = wv + 4 * h;
            ushort4 id4 = ((const ushort4*)s_idx)[u];
            float v0 = xb[(int)id4.x * NC + lane];
            float v1 = xb[(int)id4.y * NC + lane];
            float v2 = xb[(int)id4.z * NC + lane];
            float v3 = xb[(int)id4.w * NC + lane];
            int j0 = u * 4;
            float4 f;
            f.x = (j0 + 0 < m) ? v0 : 3.0e38f;
            f.y = (j0 + 1 < m) ? v1 : 3.0e38f;
            f.z = (j0 + 2 < m) ? v2 : 3.0e38f;
            f.w = (j0 + 3 < m) ? v3 : 3.0e38f;
            s_q4[lane * STR4 + u] = f;
        }
        __syncthreads();
        const float4* basep = s_q4 + lane * STR4;
        #pragma unroll
        for (int h = 0; h < 4; ++h) {
            int cq = wv + 4 * h;
            float4 c4 = basep[cq];
            int rs0=0,rl0=0, rs1=0,rl1=0, rs2=0,rl2=0, rs3=0,rl3=0;
            #pragma unroll
            for (int jq = 0; jq < 16; ++jq) {
                float4 v = basep[jq];
                rs0 += (v.x <  c4.x)+(v.y <  c4.x)+(v.z <  c4.x)+(v.w <  c4.x);
                rl0 += (v.x <= c4.x)+(v.y <= c4.x)+(v.z <= c4.x)+(v.w <= c4.x);
                rs1 += (v.x <  c4.y)+(v.y <  c4.y)+(v.z <  c4.y)+(v.w <  c4.y);
                rl1 += (v.x <= c4.y)+(v.y <= c4.y)+(v.z <= c4.y)+(v.w <= c4.y);
                rs2 += (v.x <  c4.z)+(v.y <  c4.z)+(v.z <  c4.z)+(v.w <  c4.z);
                rl2 += (v.x <= c4.z)+(v.y <= c4.z)+(v.z <= c4.z)+(v.w <= c4.z);
                rs3 += (v.x <  c4.w)+(v.y <  c4.w)+(v.z <  c4.w)+(v.w <  c4.w);
                rl3 += (v.x <= c4.w)+(v.y <= c4.w)+(v.z <= c4.w)+(v.w <= c4.w);
            }
            float ce[4] = {c4.x, c4.y, c4.z, c4.w};
            int rsa[4] = {rs0, rs1, rs2, rs3};
            int rla[4] = {rl0, rl1, rl2, rl3};
            #pragma unroll
            for (int q = 0; q < 4; ++q) {
                #pragma unroll
                for (int t = 0; t < 3; ++t) {
                    if (rsa[q] <= tlo[t] && tlo[t] < rla[q]) s_qv[lane*8 + 2*t]   = ce[q];
                    if (rsa[q] <= thi[t] && thi[t] < rla[q]) s_qv[lane*8 + 2*t+1] = ce[q];
                }
            }
        }
    } else {
        // correctness-only fallback (m > 64; never triggers on bench data)
        if (tid < NC) {
            int c = tid;
            for (int j1 = 0; j1 < NN; ++j1) {
                if (!((s_vf[j1 >> 6] >> (j1 & 63)) & 1ull)) continue;
                float v1 = xb[j1 * NC + c];
                int rs = 0, rl = 0;
                for (int j2 = 0; j2 < NN; ++j2) {
                    if (!((s_vf[j2 >> 6] >> (j2 & 63)) & 1ull)) continue;
                    float v2 = xb[j2 * NC + c];
                    rs += v2 < v1;
                    rl += v2 <= v1;
                }
                #pragma unroll
                for (int t = 0; t < 3; ++t) {
                    if (rs <= tlo[t] && tlo[t] < rl) s_qv[c*8 + 2*t]   = v1;
                    if (rs <= thi[t] && thi[t] < rl) s_qv[c*8 + 2*t+1] = v1;
                }
            }
        }
    }
    __syncthreads();

    // ---- MLP scratch overlays the (now dead) staging buffer ----
    float* s_mlp  = (float*)s_q4;
    float* s_out  = s_mlp;               // [0,64)
    float* s_h    = s_mlp + 64;          // [64,192)
    float* s_hp   = s_mlp + 256;         // [256,512)
    float* s_part = s_mlp + 512;         // [512,768)

    if (tid < NC) {                      // out = x + sum wt * lerp(q_lo, q_hi)
        float agg = 0.0f;
        #pragma unroll
        for (int t = 0; t < 3; ++t) {
            float q = s_qv[tid * 8 + 2 * t] * (1.0f - tfrac[t])
                    + s_qv[tid * 8 + 2 * t + 1] * tfrac[t];
            agg += wts[t] * q;
        }
        s_out[tid] = xval + agg;
    }
    __syncthreads();

    // ---- MLP1: 256 threads = 128 k x 2 cc-halves ----
    {
        int k = tid & 127, g = tid >> 7;
        float acc = 0.0f;
        if (USE_WT) {
            const float4* w = (const float4*)(W1T + k * 64 + g * 32);
            #pragma unroll
            for (int q = 0; q < 8; ++q) {
                float4 wq = w[q];
                int cc = g * 32 + q * 4;
                acc += wq.x * s_out[cc] + wq.y * s_out[cc + 1]
                     + wq.z * s_out[cc + 2] + wq.w * s_out[cc + 3];
            }
        } else {
            for (int cc = g * 32; cc < g * 32 + 32; ++cc)
                acc += s_out[cc] * W1[cc * NH + k];
        }
        s_hp[g * NH + k] = acc;
    }
    __syncthreads();
    if (tid < NH) {
        float a = s_hp[tid] + s_hp[NH + tid] + b1[tid];
        s_h[tid] = a > 0.0f ? a : 0.0f;
    }
    __syncthreads();

    // ---- MLP2: 256 threads = 64 o x 4 k-quarters ----
    {
        int o = tid & 63, g = tid >> 6;
        float acc = 0.0f;
        if (USE_WT) {
            const float4* w = (const float4*)(W2T + o * 128 + g * 32);
            #pragma unroll
            for (int q = 0; q < 8; ++q) {
                float4 wq = w[q];
                int k = g * 32 + q * 4;
                acc += wq.x * s_h[k] + wq.y * s_h[k + 1]
                     + wq.z * s_h[k + 2] + wq.w * s_h[k + 3];
            }
        } else {
            for (int k = g * 32; k < g * 32 + 32; ++k)
                acc += s_h[k] * W2[k * NCO + o];
        }
        s_part[g * NCO + o] = acc;
    }
    __syncthreads();
    if (tid < NCO)
        outp[tid] = s_part[tid] + s_part[64 + tid] + s_part[128 + tid]
                  + s_part[192 + tid] + b2[tid];
}

extern "C" void kernel_launch(void* const* d_in, const int* in_sizes, int n_in,
                              void* d_out, int out_size, void* d_ws, size_t ws_size,
                              hipStream_t stream) {
    const float* x   = (const float*)d_in[0];
    const float* adj = (const float*)d_in[1];
    const void* mask = d_in[2];
    const float* W1  = (const float*)d_in[3];
    const float* b1  = (const float*)d_in[4];
    const float* W2  = (const float*)d_in[5];
    const float* b2  = (const float*)d_in[6];
    float* out = (float*)d_out;

    uint64_t* validbits = (uint64_t*)d_ws;               // 128 KB
    float* W1T = (float*)((char*)d_ws + 131072);         // 32 KB
    float* W2T = W1T + 8192;                             // 32 KB
    int dowt = (ws_size >= 196608) ? 1 : 0;

    prep_kernel<<<512, 256, 0, stream>>>(adj, mask, W1, W2, validbits, W1T, W2T, dowt);
    if (dowt)
        fused_kernel<true><<<NB * NN, 256, 0, stream>>>(
            x, mask, W1, b1, W2, b2, validbits, W1T, W2T, out);
    else
        fused_kernel<false><<<NB * NN, 256, 0, stream>>>(
            x, mask, W1, b1, W2, b2, validbits, W1T, W2T, out);
}

// Round 7
// 115.544 us; speedup vs baseline: 1.5097x; 1.0742x over previous
//
#include <hip/hip_runtime.h>
#include <stdint.h>

#define NB 4
#define NN 512
#define NC 64
#define NH 128
#define NCO 64
#define MAXM 64          // fast-path cap on valid count
#define SST 65           // dword stride per channel (odd -> conflict-free)
#define FBIG 3.0e38f

// mask dtype decode: int32 (w0==1), float32 (w0==0x3f800000), else packed bytes.
__device__ inline bool read_mask(const void* mp, int idx) {
    const int* ip = (const int*)mp;
    int w0 = ip[0];
    if (w0 == 1) return ip[idx] != 0;
    if (w0 == 0x3f800000) return ((const float*)mp)[idx] != 0.0f;
    return ((const unsigned char*)mp)[idx] != 0;
}

// One wave per row: neighbor census -> validbits = neighbors surviving row i's
// own dilation removal (self excluded). valid(i,j) = vb_i[j] && vb_j[i].
// Blocks 0..63 also transpose W1/W2.
__global__ __launch_bounds__(256) void prep_kernel(
        const float* __restrict__ adj, const void* __restrict__ maskp,
        const float* __restrict__ W1, const float* __restrict__ W2,
        uint64_t* __restrict__ validbits, float* __restrict__ W1T,
        float* __restrict__ W2T, int dowt)
{
    int wave = (blockIdx.x * 256 + threadIdx.x) >> 6;
    int lane = threadIdx.x & 63;
    if (wave < NB * NN) {
        int i = wave & (NN - 1);
        const float* arow = adj + (size_t)wave * NN;
        uint64_t ball[8];
        int m = 0;
        #pragma unroll
        for (int k = 0; k < 8; ++k) {
            int j = k * 64 + lane;
            bool f = (j != i) && (arow[j] > 0.0f);
            uint64_t bl = __ballot(f);
            ball[k] = bl;
            m += __popcll(bl);
        }
        int skip = (m > 10) ? ((m + 1) >> 1) : 1;   // ceil(m/2), K_DIL=2
        bool dodil = (skip > 1) && read_mask(maskp, wave);
        int skip2 = skip * 2;
        int prefix = 0;
        #pragma unroll
        for (int k = 0; k < 8; ++k) {
            uint64_t bl = ball[k];
            int rank1 = prefix + __popcll(bl & ((1ull << lane) - 1ull)) + 1;
            bool f = (bl >> lane) & 1ull;
            // (rank % skip)==0 <=> rank==skip || rank==2*skip  (rank <= m <= 2*skip)
            bool keep = f && !(dodil && (rank1 == skip || rank1 == skip2));
            uint64_t vb = __ballot(keep);
            if (lane == 0) validbits[(size_t)wave * 8 + k] = vb;
            prefix += __popcll(bl);
        }
    }
    if (dowt) {
        int e = blockIdx.x * 256 + threadIdx.x;
        if (e < 8192) {                       // W1T[k][c] = W1[c][k]
            int k = e >> 6, c = e & 63;
            W1T[e] = W1[c * NH + k];
        } else if (e < 16384) {               // W2T[o][k] = W2[k][o]
            int e2 = e - 8192;
            int o = e2 >> 7, k = e2 & 127;
            W2T[e2] = W2[k * NCO + o];
        }
    }
}

// Bitonic merge-sort across WIDTH lanes (values one per logical lane l).
// After the network, values are ascending in l. WIDTH = 32 or 64.
template<int WIDTH>
__device__ inline float bitonic_sort_lane(float v, int lane) {
    #pragma unroll
    for (int k = 2; k <= WIDTH; k <<= 1) {
        #pragma unroll
        for (int d = k >> 1; d >= 1; d >>= 1) {
            float vp = __shfl_xor(v, d);
            bool keepmin = ((lane & k) == 0) == ((lane & d) == 0);
            v = keepmin ? fminf(v, vp) : fmaxf(v, vp);
        }
    }
    return v;
}

// One 256-thread block per row. Valid list via precomputed validbits,
// conflict-free LDS transpose stage, per-wave BITONIC SORT quantiles
// (replaces O(m^2) rank counting — round 6 showed that was VALU-bound),
// fused GIN MLP on overlaid LDS. No launch_bounds: occupancy proven
// non-binding (r4/r5); register freedom matters more.
template<bool USE_WT>
__global__ void fused_kernel(
        const float* __restrict__ x,
        const void* __restrict__ maskp,
        const float* __restrict__ W1,
        const float* __restrict__ b1,
        const float* __restrict__ W2,
        const float* __restrict__ b2,
        const uint64_t* __restrict__ validbits,
        const float* __restrict__ W1T,
        const float* __restrict__ W2T,
        float* __restrict__ out)
{
    int row = blockIdx.x;                // b*NN + i
    int b = row >> 9, i = row & (NN - 1);
    int tid = threadIdx.x, lane = tid & 63, wv = tid >> 6;
    float* outp = out + (size_t)row * NCO;

    if (!read_mask(maskp, row)) {        // masked row: explicit zeros (out poisoned)
        if (tid < NCO) outp[tid] = 0.0f;
        return;
    }

    __shared__ float sv[NC * SST];               // 16640 B stage; reused as MLP scratch
    __shared__ float s_agg[NC];                  // per-channel weighted-quantile sum
    __shared__ __align__(8) uint16_t s_idx[MAXM];// valid list (unordered)
    __shared__ uint64_t s_vb[8];                 // row i's validbits (no self)
    __shared__ uint64_t s_vf[8];                 // full pairwise-valid bits (w/ self)
    __shared__ int s_cnt;

    float xval = (tid < NC) ? x[(size_t)row * NC + tid] : 0.0f;  // prefetch
    if (tid < 8) s_vb[tid] = validbits[(size_t)row * 8 + tid];
    if (tid < MAXM) s_idx[tid] = (uint16_t)i;    // safe-address padding; slot 0=self
    if (tid == 0) s_cnt = 1;
    __syncthreads();

    // ---- P2: valid(i,j) = vb_i[j] && vb_j[i]; list append + full-valid ballot ----
    int ic = i >> 6;
    uint64_t imask = 1ull << (i & 63);
    #pragma unroll
    for (int it = 0; it < 2; ++it) {
        int j = tid + it * 256;
        bool nb = ((s_vb[j >> 6] >> (j & 63)) & 1ull) &&
                  (validbits[((size_t)(b * NN + j)) * 8 + ic] & imask);
        uint64_t bl = __ballot(nb || (j == i));
        if (lane == 0) s_vf[it * 4 + wv] = bl;
        if (nb) {
            int p = atomicAdd(&s_cnt, 1);
            if (p < MAXM) s_idx[p] = (uint16_t)j;
        }
    }
    __syncthreads();
    int m = s_cnt;                       // >= 1 (self-loop)

    // ---- quantile positions (torch 'linear') ----
    float mf = (float)m;
    const float taus[3] = {0.25f, 0.5f, 0.75f};
    const float wts[3]  = {0.25f, 0.5f, 0.25f};
    int tlo[3], thi[3];
    float tfrac[3];
    #pragma unroll
    for (int t = 0; t < 3; ++t) {
        float pos = taus[t] * (mf - 1.0f);
        float fl = floorf(pos);
        tlo[t] = (int)fl;
        thi[t] = (int)ceilf(pos);
        tfrac[t] = pos - fl;
    }

    const float* xb = x + (size_t)b * NN * NC;

    if (m <= 32) {
        // ---- stage j=0..31 transposed: sv[c*SST + j]; writes conflict-free ----
        #pragma unroll
        for (int h = 0; h < 2; ++h) {
            ushort4 id4 = ((const ushort4*)s_idx)[wv * 2 + h];
            int j0 = wv * 8 + h * 4;
            float v0 = xb[(int)id4.x * NC + lane];
            float v1 = xb[(int)id4.y * NC + lane];
            float v2 = xb[(int)id4.z * NC + lane];
            float v3 = xb[(int)id4.w * NC + lane];
            sv[lane * SST + j0 + 0] = (j0 + 0 < m) ? v0 : FBIG;
            sv[lane * SST + j0 + 1] = (j0 + 1 < m) ? v1 : FBIG;
            sv[lane * SST + j0 + 2] = (j0 + 2 < m) ? v2 : FBIG;
            sv[lane * SST + j0 + 3] = (j0 + 3 < m) ? v3 : FBIG;
        }
        __syncthreads();
        // ---- sort-32: two channels per wave (lane halves); 8 pairs per wave ----
        int half = lane >> 5, l = lane & 31;
        #pragma unroll
        for (int pp = 0; pp < 8; ++pp) {
            int p = pp * 4 + wv;                 // pair index 0..31
            int c = p * 2 + half;
            float v = sv[c * SST + l];
            v = bitonic_sort_lane<32>(v, l);
            float agg = 0.0f;
            #pragma unroll
            for (int t = 0; t < 3; ++t) {
                float vlo = __shfl(v, (half << 5) | tlo[t]);
                float vhi = __shfl(v, (half << 5) | thi[t]);
                agg += wts[t] * (vlo * (1.0f - tfrac[t]) + vhi * tfrac[t]);
            }
            if (l == 0) s_agg[c] = agg;
        }
    } else if (m <= MAXM) {
        // ---- stage j=0..63 transposed ----
        #pragma unroll
        for (int h = 0; h < 4; ++h) {
            ushort4 id4 = ((const ushort4*)s_idx)[wv * 4 + h];
            int j0 = wv * 16 + h * 4;
            float v0 = xb[(int)id4.x * NC + lane];
            float v1 = xb[(int)id4.y * NC + lane];
            float v2 = xb[(int)id4.z * NC + lane];
            float v3 = xb[(int)id4.w * NC + lane];
            sv[lane * SST + j0 + 0] = (j0 + 0 < m) ? v0 : FBIG;
            sv[lane * SST + j0 + 1] = (j0 + 1 < m) ? v1 : FBIG;
            sv[lane * SST + j0 + 2] = (j0 + 2 < m) ? v2 : FBIG;
            sv[lane * SST + j0 + 3] = (j0 + 3 < m) ? v3 : FBIG;
        }
        __syncthreads();
        // ---- sort-64: one channel per wave; 16 channels per wave ----
        #pragma unroll
        for (int cc = 0; cc < 16; ++cc) {
            int c = cc * 4 + wv;
            float v = sv[c * SST + lane];
            v = bitonic_sort_lane<64>(v, lane);
            float agg = 0.0f;
            #pragma unroll
            for (int t = 0; t < 3; ++t) {
                float vlo = __shfl(v, tlo[t]);
                float vhi = __shfl(v, thi[t]);
                agg += wts[t] * (vlo * (1.0f - tfrac[t]) + vhi * tfrac[t]);
            }
            if (lane == 0) s_agg[c] = agg;
        }
    } else {
        // correctness-only fallback (m > 64; never triggers on bench data)
        if (tid < NC) {
            int c = tid;
            float qv[6];
            for (int j1 = 0; j1 < NN; ++j1) {
                if (!((s_vf[j1 >> 6] >> (j1 & 63)) & 1ull)) continue;
                float v1 = xb[j1 * NC + c];
                int rs = 0, rl = 0;
                for (int j2 = 0; j2 < NN; ++j2) {
                    if (!((s_vf[j2 >> 6] >> (j2 & 63)) & 1ull)) continue;
                    float v2 = xb[j2 * NC + c];
                    rs += v2 < v1;
                    rl += v2 <= v1;
                }
                #pragma unroll
                for (int t = 0; t < 3; ++t) {
                    if (rs <= tlo[t] && tlo[t] < rl) qv[2 * t]     = v1;
                    if (rs <= thi[t] && thi[t] < rl) qv[2 * t + 1] = v1;
                }
            }
            float agg = 0.0f;
            #pragma unroll
            for (int t = 0; t < 3; ++t)
                agg += wts[t] * (qv[2 * t] * (1.0f - tfrac[t]) + qv[2 * t + 1] * tfrac[t]);
            s_agg[c] = agg;
        }
    }
    __syncthreads();

    // ---- MLP scratch overlays the (now dead) staging buffer ----
    float* s_out  = sv;                  // [0,64)
    float* s_h    = sv + 64;             // [64,192)
    float* s_hp   = sv + 256;            // [256,512)
    float* s_part = sv + 512;            // [512,768)

    if (tid < NC)                        // out = x + weighted-quantile agg
        s_out[tid] = xval + s_agg[tid];
    __syncthreads();

    // ---- MLP1: 256 threads = 128 k x 2 cc-halves ----
    {
        int k = tid & 127, g = tid >> 7;
        float acc = 0.0f;
        if (USE_WT) {
            const float4* w = (const float4*)(W1T + k * 64 + g * 32);
            #pragma unroll
            for (int q = 0; q < 8; ++q) {
                float4 wq = w[q];
                int cc = g * 32 + q * 4;
                acc += wq.x * s_out[cc] + wq.y * s_out[cc + 1]
                     + wq.z * s_out[cc + 2] + wq.w * s_out[cc + 3];
            }
        } else {
            for (int cc = g * 32; cc < g * 32 + 32; ++cc)
                acc += s_out[cc] * W1[cc * NH + k];
        }
        s_hp[g * NH + k] = acc;
    }
    __syncthreads();
    if (tid < NH) {
        float a = s_hp[tid] + s_hp[NH + tid] + b1[tid];
        s_h[tid] = a > 0.0f ? a : 0.0f;
    }
    __syncthreads();

    // ---- MLP2: 256 threads = 64 o x 4 k-quarters ----
    {
        int o = tid & 63, g = tid >> 6;
        float acc = 0.0f;
        if (USE_WT) {
            const float4* w = (const float4*)(W2T + o * 128 + g * 32);
            #pragma unroll
            for (int q = 0; q < 8; ++q) {
                float4 wq = w[q];
                int k = g * 32 + q * 4;
                acc += wq.x * s_h[k] + wq.y * s_h[k + 1]
                     + wq.z * s_h[k + 2] + wq.w * s_h[k + 3];
            }
        } else {
            for (int k = g * 32; k < g * 32 + 32; ++k)
                acc += s_h[k] * W2[k * NCO + o];
        }
        s_part[g * NCO + o] = acc;
    }
    __syncthreads();
    if (tid < NCO)
        outp[tid] = s_part[tid] + s_part[64 + tid] + s_part[128 + tid]
                  + s_part[192 + tid] + b2[tid];
}

extern "C" void kernel_launch(void* const* d_in, const int* in_sizes, int n_in,
                              void* d_out, int out_size, void* d_ws, size_t ws_size,
                              hipStream_t stream) {
    const float* x   = (const float*)d_in[0];
    const float* adj = (const float*)d_in[1];
    const void* mask = d_in[2];
    const float* W1  = (const float*)d_in[3];
    const float* b1  = (const float*)d_in[4];
    const float* W2  = (const float*)d_in[5];
    const float* b2  = (const float*)d_in[6];
    float* out = (float*)d_out;

    uint64_t* validbits = (uint64_t*)d_ws;               // 128 KB
    float* W1T = (float*)((char*)d_ws + 131072);         // 32 KB
    float* W2T = W1T + 8192;                             // 32 KB
    int dowt = (ws_size >= 196608) ? 1 : 0;

    prep_kernel<<<512, 256, 0, stream>>>(adj, mask, W1, W2, validbits, W1T, W2T, dowt);
    if (dowt)
        fused_kernel<true><<<NB * NN, 256, 0, stream>>>(
            x, mask, W1, b1, W2, b2, validbits, W1T, W2T, out);
    else
        fused_kernel<false><<<NB * NN, 256, 0, stream>>>(
            x, mask, W1, b1, W2, b2, validbits, W1T, W2T, out);
}